// Round 4
// baseline (1419.224 us; speedup 1.0000x reference)
//
#include <hip/hip_runtime.h>

#define SEQ 512
#define BATCH 256
#define INDIM 256
#define MLP 128
#define M_ROWS (SEQ * BATCH)        // 131072
#define PRE_STRIDE 136              // 128 mlp-pre + 4 gate-pre + 4 pad
#define AUX_OFF ((size_t)M_ROWS * PRE_STRIDE)  // in floats

#define NBLK_REC 256
#define NBLK_GEMM (M_ROWS / 128)    // 1024

// Producer->consumer handshake. Monotone across graph replays: g_epoch is
// bumped once per launch by prep_kernel; gemm block gblk does a release
// fetch_add on g_flags[gblk]; rec waits for flags >= epoch. Zero-initialized
// at module load; never reset (monotone >= comparison makes replays safe).
__device__ unsigned g_epoch;
__device__ unsigned g_flags[NBLK_GEMM];

// ---------------------------------------------------------------------------
// Kernel 1: prep — column sums + epoch bump for this launch.
// ---------------------------------------------------------------------------
__global__ __launch_bounds__(256) void prep_kernel(
    const float* __restrict__ W1,
    const float* __restrict__ Wf, const float* __restrict__ Wi,
    const float* __restrict__ Wg, const float* __restrict__ Wo,
    const float* __restrict__ bf, const float* __restrict__ bi,
    const float* __restrict__ bg, const float* __restrict__ bo,
    float* __restrict__ aux) {
  const int tid = threadIdx.x;
  if (tid < 128) {
    float s = 0.f;
    for (int k = 0; k < 256; ++k) s += W1[(size_t)(256 + k) * 128 + tid];
    aux[tid] = s;
  } else if (tid < 132) {
    const int g = tid - 128;
    const float* w = (g == 0) ? Wf : (g == 1) ? Wi : (g == 2) ? Wg : Wo;
    float s = 0.f;
    for (int k = 0; k < 256; ++k) s += w[256 + k];
    aux[128 + g] = s;
  } else if (tid < 136) {
    const int g = tid - 132;
    const float* bp = (g == 0) ? bf : (g == 1) ? bi : (g == 2) ? bg : bo;
    aux[132 + g] = bp[0];
  }
  if (tid == 0)
    __hip_atomic_fetch_add(&g_epoch, 1u, __ATOMIC_RELAXED,
                           __HIP_MEMORY_SCOPE_AGENT);
}

// ---------------------------------------------------------------------------
// Fused kernel: blocks [0,256) = rec chains (R5 rec verbatim + flag waits);
// blocks [256,1280) = R5 gemm verbatim + release-flag publish.
//
// R9 post-mortem: av[gr] runtime-indexed local array -> scratch (rule #20),
// gemm 306->425 us. Reverted to R5's ds_read gate. R8 post-mortem: no
// global_load_lds staging in rec (compiler-forced vmcnt(0) drain). This round:
// overlap gemm under rec's latency shadow (rec = 1 wave/CU, VALUBusy 12.5% —
// 87% of every CU idle while gemm waits its turn on the stream).
//
// Safety: producers never wait -> deadlock-free under ANY dispatch order.
// Producer publish: __syncthreads (drains stores to L2) + __threadfence
// (L2 writeback to die-level L3) + release fetch_add. Consumer: acquire load
// of the flag before issuing that row's prefetch (probe issued early in the
// step so ~300cy latency hides under the dot); PRE lines are cold in the
// consumer's L1/L2 -> no stale-copy hazard.
// ---------------------------------------------------------------------------
#define BK 16
#define LDX 132  // padded LDS row stride (words)

__device__ __forceinline__ float sigmoid_f(float x) {
  return __fdividef(1.0f, 1.0f + __expf(-x));
}
__device__ __forceinline__ float tanh_f(float x) {
  const float e = __expf(-2.0f * x);
  return __fdividef(1.0f - e, 1.0f + e);
}
__device__ __forceinline__ float readlane_f(float v, int lane) {
  return __int_as_float(__builtin_amdgcn_readlane(__float_as_int(v), lane));
}

__device__ __forceinline__ void spin_flag(const unsigned* fp, unsigned target) {
  int guard = 0;
  while (__hip_atomic_load(fp, __ATOMIC_ACQUIRE, __HIP_MEMORY_SCOPE_AGENT) <
         target) {
    __builtin_amdgcn_s_sleep(2);
    if (++guard > (1 << 19)) break;  // pathology escape: fail loud, not hang
  }
}

__global__ __launch_bounds__(256) void fused_kernel(
    const float* __restrict__ X,    // [M_ROWS][256]
    const float* __restrict__ W1,   // [512][128]
    const float* __restrict__ b1p,  // [128]
    const float* __restrict__ Wf, const float* __restrict__ Wi,
    const float* __restrict__ Wg, const float* __restrict__ Wo,
    const float* __restrict__ bfp, const float* __restrict__ bip,
    const float* __restrict__ bgp, const float* __restrict__ bop,
    const float* __restrict__ W2, const float* __restrict__ b2,
    const float* __restrict__ aux,
    float* __restrict__ PRE, float* __restrict__ out) {
  __shared__ __align__(16) float lds[BK * LDX * 2 + BK * 4];  // 17 KB union

  if (blockIdx.x >= NBLK_REC) {
    // ===================== GEMM role (R5 verbatim) =====================
    float* Xs = lds;                  // [kk][row], row-padded
    float* Ws = lds + BK * LDX;       // [kk][col]
    float* Wgs = lds + 2 * BK * LDX;  // [kk][gate]

    const int tid = threadIdx.x;
    const int gblk = blockIdx.x - NBLK_REC;
    const int tx = tid & 15, ty = tid >> 4;        // 16x16 thread grid
    const int r_st = tid >> 1, kh = (tid & 1) * 8; // X staging role
    const int wk = tid >> 4, wn = (tid & 15) * 8;  // W staging role
    const int r2 = tid >> 1, gp = (tid & 1) * 2;   // gate compute role

    const size_t rowbase = (size_t)gblk * 128;

    float acc[8][8] = {};
    float ga = 0.f, gb = 0.f;

    for (int kc = 0; kc < 256; kc += BK) {
      const float4 xa = *(const float4*)&X[(rowbase + r_st) * 256 + kc + kh];
      const float4 xb = *(const float4*)&X[(rowbase + r_st) * 256 + kc + kh + 4];
      const float4 wa = *(const float4*)&W1[(size_t)(kc + wk) * 128 + wn];
      const float4 wb = *(const float4*)&W1[(size_t)(kc + wk) * 128 + wn + 4];
      float wgv = 0.f;
      if (tid < 64) {
        const int kk = tid >> 2, g = tid & 3;
        const float* w = (g == 0) ? Wf : (g == 1) ? Wi : (g == 2) ? Wg : Wo;
        wgv = w[kc + kk];
      }
      __syncthreads();
      Xs[(kh + 0) * LDX + r_st] = xa.x;
      Xs[(kh + 1) * LDX + r_st] = xa.y;
      Xs[(kh + 2) * LDX + r_st] = xa.z;
      Xs[(kh + 3) * LDX + r_st] = xa.w;
      Xs[(kh + 4) * LDX + r_st] = xb.x;
      Xs[(kh + 5) * LDX + r_st] = xb.y;
      Xs[(kh + 6) * LDX + r_st] = xb.z;
      Xs[(kh + 7) * LDX + r_st] = xb.w;
      *(float4*)&Ws[wk * LDX + wn] = wa;
      *(float4*)&Ws[wk * LDX + wn + 4] = wb;
      if (tid < 64) Wgs[tid] = wgv;
      __syncthreads();

#pragma unroll
      for (int kk = 0; kk < BK; ++kk) {
        const float4 a0 = *(const float4*)&Xs[kk * LDX + ty * 8];
        const float4 a1 = *(const float4*)&Xs[kk * LDX + ty * 8 + 4];
        const float4 c0 = *(const float4*)&Ws[kk * LDX + tx * 8];
        const float4 c1 = *(const float4*)&Ws[kk * LDX + tx * 8 + 4];
        const float av[8] = {a0.x, a0.y, a0.z, a0.w, a1.x, a1.y, a1.z, a1.w};
        const float bv[8] = {c0.x, c0.y, c0.z, c0.w, c1.x, c1.y, c1.z, c1.w};
#pragma unroll
        for (int i = 0; i < 8; ++i)
#pragma unroll
          for (int j = 0; j < 8; ++j)
            acc[i][j] = fmaf(av[i], bv[j], acc[i][j]);
        const float xv = Xs[kk * LDX + r2];
        ga = fmaf(xv, Wgs[kk * 4 + gp], ga);
        gb = fmaf(xv, Wgs[kk * 4 + gp + 1], gb);
      }
    }

    float bias[8];
    {
      const float4 u0 = *(const float4*)&b1p[tx * 8];
      const float4 u1 = *(const float4*)&b1p[tx * 8 + 4];
      bias[0] = u0.x; bias[1] = u0.y; bias[2] = u0.z; bias[3] = u0.w;
      bias[4] = u1.x; bias[5] = u1.y; bias[6] = u1.z; bias[7] = u1.w;
    }
#pragma unroll
    for (int i = 0; i < 8; ++i) {
      const size_t row = rowbase + ty * 8 + i;
      float4 o0, o1;
      o0.x = acc[i][0] + bias[0]; o0.y = acc[i][1] + bias[1];
      o0.z = acc[i][2] + bias[2]; o0.w = acc[i][3] + bias[3];
      o1.x = acc[i][4] + bias[4]; o1.y = acc[i][5] + bias[5];
      o1.z = acc[i][6] + bias[6]; o1.w = acc[i][7] + bias[7];
      *(float4*)&PRE[row * PRE_STRIDE + tx * 8] = o0;
      *(float4*)&PRE[row * PRE_STRIDE + tx * 8 + 4] = o1;
    }
    {
      const float ab = (gp == 0) ? bfp[0] : bgp[0];
      const float bb2 = (gp == 0) ? bip[0] : bop[0];
      float2 og;
      og.x = ga + ab; og.y = gb + bb2;
      *(float2*)&PRE[(rowbase + r2) * PRE_STRIDE + 128 + gp] = og;
    }

    // -------- publish: all stores drained (barrier implies vmcnt(0)),
    // L2 written back to L3, then release-increment this block's flag. ----
    __syncthreads();
    if (tid == 0) {
      __threadfence();
      __hip_atomic_fetch_add(&g_flags[gblk], 1u, __ATOMIC_RELEASE,
                             __HIP_MEMORY_SCOPE_AGENT);
    }
    return;
  }

  // ======================= REC role (R5 verbatim + waits) ==================
  const int l = threadIdx.x;
  if (l >= 64) return;  // 1 wave per chain
  float* h1s = lds;     // 128 floats of the union

  const int b = blockIdx.x;
  const int m = l & 31, half = l >> 5;
  const int g = m >> 3;             // my gate group: 0=f 1=i 2=g 3=o
  const int g8 = g * 8;             // first column of my group

  // W2 fragment in registers: lane (m,half) holds W2[half*64+u][m]
  float w2r[64];
#pragma unroll
  for (int u = 0; u < 64; ++u) w2r[u] = W2[(size_t)(half * 64 + u) * 32 + m];
  const float4 b2a = *(const float4*)&b2[g8];
  const float4 b2b = *(const float4*)&b2[g8 + 4];
  const float2 s1 = *(const float2*)&aux[2 * l];
  const float4 sg = *(const float4*)&aux[128];  // sf, si, sg, so

  const unsigned target =
      __hip_atomic_load(&g_epoch, __ATOMIC_RELAXED, __HIP_MEMORY_SCOPE_AGENT);
  const int hb = (b >= 128) ? 1 : 0;  // my half-row producer parity

  // wait for rows 0 and 1 (producers 2*0+hb, 2*1+hb)
  spin_flag(&g_flags[0 + hb], target);
  spin_flag(&g_flags[2 + hb], target);

  float h = 0.f, c = 0.f;

  const float* pr0 = PRE + (size_t)b * PRE_STRIDE;
  const size_t ts = (size_t)BATCH * PRE_STRIDE;

  // depth-2 rotating prefetch
  float2 p0 = *(const float2*)(pr0 + 0 * ts + 2 * l);
  float4 g0 = *(const float4*)(pr0 + 0 * ts + 128);
  float2 p1 = *(const float2*)(pr0 + 1 * ts + 2 * l);
  float4 g1 = *(const float4*)(pr0 + 1 * ts + 128);

  const float4* h1p = (const float4*)&h1s[half * 64];

  for (int t = 0; t < SEQ; ++t) {
    const int tn = (t + 2 < SEQ) ? (t + 2) : (SEQ - 1);
    // early flag probe for row tn — acquire; latency hides under the dot
    const unsigned fv = __hip_atomic_load(
        &g_flags[2 * tn + hb], __ATOMIC_ACQUIRE, __HIP_MEMORY_SCOPE_AGENT);

    // h1 = relu(pre + h*s1)
    const float h10 = fmaxf(fmaf(h, s1.x, p0.x), 0.f);
    const float h11 = fmaxf(fmaf(h, s1.y, p0.y), 0.f);

    // publish h1 (the step's only LDS write); DS pipe is in-order per wave.
    ((float2*)h1s)[l] = make_float2(h10, h11);
    asm volatile("" ::: "memory");  // compiler barrier only — no s_waitcnt

    // classical gates — independent VALU work overlapping LDS latency
    const float zf = fmaf(h, sg.x, g0.x);
    const float zi = fmaf(h, sg.y, g0.y);
    const float zg = fmaf(h, sg.z, g0.z);
    const float zo = fmaf(h, sg.w, g0.w);
    const float cf = sigmoid_f(zf);
    const float ci = sigmoid_f(zi);
    const float cg = tanh_f(zg);
    const float co = sigmoid_f(zo);

    // row tn must be published before its prefetch issues (slow path rare)
    if (fv < target) spin_flag(&g_flags[2 * tn + hb], target);

    // rotate prefetch (depth 2)
    p0 = p1; g0 = g1;
    p1 = *(const float2*)(pr0 + (size_t)tn * ts + 2 * l);
    g1 = *(const float4*)(pr0 + (size_t)tn * ts + 128);

    // partial[m,half] = sum over my K-half of h1[j]*W2[j][m]
    float q0 = 0.f, q1 = 0.f, q2 = 0.f, q3 = 0.f;
#pragma unroll
    for (int jj = 0; jj < 16; ++jj) {
      const float4 hv = h1p[jj];
      q0 = fmaf(hv.x, w2r[4 * jj + 0], q0);
      q1 = fmaf(hv.y, w2r[4 * jj + 1], q1);
      q2 = fmaf(hv.z, w2r[4 * jj + 2], q2);
      q3 = fmaf(hv.w, w2r[4 * jj + 3], q3);
    }
    const float part = (q0 + q1) + (q2 + q3);

    // ONE pipelined 16-shfl burst: both halves' partials for my group's 8 m's
    const float a0 = __shfl(part, g8 + 0, 64), b0 = __shfl(part, 32 + g8 + 0, 64);
    const float a1 = __shfl(part, g8 + 1, 64), b1 = __shfl(part, 32 + g8 + 1, 64);
    const float a2 = __shfl(part, g8 + 2, 64), b2s = __shfl(part, 32 + g8 + 2, 64);
    const float a3 = __shfl(part, g8 + 3, 64), b3 = __shfl(part, 32 + g8 + 3, 64);
    const float a4 = __shfl(part, g8 + 4, 64), b4 = __shfl(part, 32 + g8 + 4, 64);
    const float a5 = __shfl(part, g8 + 5, 64), b5 = __shfl(part, 32 + g8 + 5, 64);
    const float a6 = __shfl(part, g8 + 6, 64), b6 = __shfl(part, 32 + g8 + 6, 64);
    const float a7 = __shfl(part, g8 + 7, 64), b7 = __shfl(part, 32 + g8 + 7, 64);

    // theta + cos, per-lane redundant (every lane evaluates ITS group)
    const float e0 = __cosf(a0 + b0 + b2a.x);
    const float e1 = __cosf(a1 + b1 + b2a.y);
    const float e2 = __cosf(a2 + b2s + b2a.z);
    const float e3 = __cosf(a3 + b3 + b2a.w);
    const float e4 = __cosf(a4 + b4 + b2b.x);
    const float e5 = __cosf(a5 + b5 + b2b.y);
    const float e6 = __cosf(a6 + b6 + b2b.z);
    const float e7 = __cosf(a7 + b7 + b2b.w);
    float p = e0, s = e0;
    p *= e1; s += p;
    p *= e2; s += p;
    p *= e3; s += p;
    p *= e4; s += p;
    p *= e5; s += p;
    p *= e6; s += p;
    p *= e7; s += p;
    const float qv = s * 0.125f;

    // one quantum activation per lane (group 2: tanh = 2*sigmoid(2x)-1)
    const float qarg = (g == 2) ? (2.0f * qv) : qv;
    const float qs = sigmoid_f(qarg);
    const float av = (g == 2) ? (2.0f * qs - 1.0f) : qs;

    // collect the 4 gate scalars via v_readlane (VALU, uniform lane indices)
    const float aF = readlane_f(av, 0);
    const float aI = readlane_f(av, 8);
    const float aG = readlane_f(av, 16);
    const float aO = readlane_f(av, 24);

    const float f  = 0.5f * (cf + aF);
    const float ii = 0.5f * (ci + aI);
    const float gg = 0.5f * (cg + aG);
    const float oo = 0.5f * (co + aO);

    c = fmaf(f, c, ii * gg);
    h = oo * tanh_f(c);

    float4 hv4o; hv4o.x = h; hv4o.y = h; hv4o.z = h; hv4o.w = h;
    *(float4*)(out + ((size_t)t * BATCH + b) * 256 + 4 * l) = hv4o;
  }

  // final (hx, cx)
  float4 hq; hq.x = h; hq.y = h; hq.z = h; hq.w = h;
  float4 cq; cq.x = c; cq.y = c; cq.z = c; cq.w = c;
  *(float4*)(out + (size_t)SEQ * BATCH * 256 + (size_t)b * 256 + 4 * l) = hq;
  *(float4*)(out + (size_t)SEQ * BATCH * 256 + (size_t)BATCH * 256 +
             (size_t)b * 256 + 4 * l) = cq;
}

// ---------------------------------------------------------------------------
extern "C" void kernel_launch(void* const* d_in, const int* in_sizes, int n_in,
                              void* d_out, int out_size, void* d_ws,
                              size_t ws_size, hipStream_t stream) {
  const float* X  = (const float*)d_in[0];
  const float* W1 = (const float*)d_in[1];
  const float* b1 = (const float*)d_in[2];
  const float* W2 = (const float*)d_in[3];
  const float* b2 = (const float*)d_in[4];
  const float* Wf = (const float*)d_in[5];
  const float* bf = (const float*)d_in[6];
  const float* Wi = (const float*)d_in[7];
  const float* bi = (const float*)d_in[8];
  const float* Wg = (const float*)d_in[9];
  const float* bg = (const float*)d_in[10];
  const float* Wo = (const float*)d_in[11];
  const float* bo = (const float*)d_in[12];

  float* ws  = (float*)d_ws;
  float* PRE = ws;
  float* aux = ws + AUX_OFF;
  float* out = (float*)d_out;

  prep_kernel<<<1, 256, 0, stream>>>(W1, Wf, Wi, Wg, Wo, bf, bi, bg, bo, aux);
  fused_kernel<<<NBLK_REC + NBLK_GEMM, 256, 0, stream>>>(
      X, W1, b1, Wf, Wi, Wg, Wo, bf, bi, bg, bo, W2, b2, aux, PRE, out);
}

// Round 5
// 1414.983 us; speedup vs baseline: 1.0030x; 1.0030x over previous
//
#include <hip/hip_runtime.h>

#define SEQ 512
#define BATCH 256
#define INDIM 256
#define MLP 128
#define M_ROWS (SEQ * BATCH)        // 131072
#define PRE_STRIDE 136              // 128 mlp-pre + 4 gate-pre + 4 pad
#define AUX_OFF ((size_t)M_ROWS * PRE_STRIDE)  // in floats

#define NBLK_REC 256
#define NBLK_GEMM (M_ROWS / 128)    // 1024

// Producer->consumer handshake. Monotone across graph replays: g_epoch is
// bumped once per launch by prep_kernel; gemm block gblk does a release
// fetch_add on g_flags[gblk]; rec waits for flags >= epoch. Zero-initialized
// at module load; never reset (monotone >= comparison makes replays safe).
__device__ unsigned g_epoch;
__device__ unsigned g_flags[NBLK_GEMM];

// ---------------------------------------------------------------------------
// Kernel 1: prep — column sums + epoch bump for this launch.
// ---------------------------------------------------------------------------
__global__ __launch_bounds__(256) void prep_kernel(
    const float* __restrict__ W1,
    const float* __restrict__ Wf, const float* __restrict__ Wi,
    const float* __restrict__ Wg, const float* __restrict__ Wo,
    const float* __restrict__ bf, const float* __restrict__ bi,
    const float* __restrict__ bg, const float* __restrict__ bo,
    float* __restrict__ aux) {
  const int tid = threadIdx.x;
  if (tid < 128) {
    float s = 0.f;
    for (int k = 0; k < 256; ++k) s += W1[(size_t)(256 + k) * 128 + tid];
    aux[tid] = s;
  } else if (tid < 132) {
    const int g = tid - 128;
    const float* w = (g == 0) ? Wf : (g == 1) ? Wi : (g == 2) ? Wg : Wo;
    float s = 0.f;
    for (int k = 0; k < 256; ++k) s += w[256 + k];
    aux[128 + g] = s;
  } else if (tid < 136) {
    const int g = tid - 132;
    const float* bp = (g == 0) ? bf : (g == 1) ? bi : (g == 2) ? bg : bo;
    aux[132 + g] = bp[0];
  }
  if (tid == 0)
    __hip_atomic_fetch_add(&g_epoch, 1u, __ATOMIC_RELAXED,
                           __HIP_MEMORY_SCOPE_AGENT);
}

// ---------------------------------------------------------------------------
// Fused kernel: blocks [0,256) = rec chains (R5 rec verbatim + flag waits);
// blocks [256,1280) = R5 gemm verbatim + release-flag publish.
//
// R10 post-mortem: default regalloc heuristic for a 256-thread block capped
// the kernel at 88 VGPRs -> rec's w2r[64] SPILLED to scratch (standalone rec
// needs 132), rec role ~2.8x slower. Fix: __launch_bounds__(256, 2) -> VGPR
// cap 512/2 = 256 >= 132, no spill; usage (~132) then gives 3 waves/SIMD at
// runtime = 1 rec + 2 gemm blocks co-resident per CU — the intended overlap.
//
// R9 post-mortem: runtime-indexed local array -> scratch (rule #20); R5's
// ds_read gate retained. R8 post-mortem: no global_load_lds in rec.
//
// Safety: producers never wait -> deadlock-free under ANY dispatch order.
// Producer publish: __syncthreads (drains stores) + __threadfence (L2->L3
// writeback) + release fetch_add. Consumer: acquire flag load before issuing
// that row's prefetch; PRE lines cold in consumer caches -> no stale copy.
// ---------------------------------------------------------------------------
#define BK 16
#define LDX 132  // padded LDS row stride (words)

__device__ __forceinline__ float sigmoid_f(float x) {
  return __fdividef(1.0f, 1.0f + __expf(-x));
}
__device__ __forceinline__ float tanh_f(float x) {
  const float e = __expf(-2.0f * x);
  return __fdividef(1.0f - e, 1.0f + e);
}
__device__ __forceinline__ float readlane_f(float v, int lane) {
  return __int_as_float(__builtin_amdgcn_readlane(__float_as_int(v), lane));
}

__device__ __forceinline__ void spin_flag(const unsigned* fp, unsigned target) {
  int guard = 0;
  while (__hip_atomic_load(fp, __ATOMIC_ACQUIRE, __HIP_MEMORY_SCOPE_AGENT) <
         target) {
    __builtin_amdgcn_s_sleep(2);
    if (++guard > (1 << 19)) break;  // pathology escape: fail loud, not hang
  }
}

__global__ __launch_bounds__(256, 2) void fused_kernel(
    const float* __restrict__ X,    // [M_ROWS][256]
    const float* __restrict__ W1,   // [512][128]
    const float* __restrict__ b1p,  // [128]
    const float* __restrict__ Wf, const float* __restrict__ Wi,
    const float* __restrict__ Wg, const float* __restrict__ Wo,
    const float* __restrict__ bfp, const float* __restrict__ bip,
    const float* __restrict__ bgp, const float* __restrict__ bop,
    const float* __restrict__ W2, const float* __restrict__ b2,
    const float* __restrict__ aux,
    float* __restrict__ PRE, float* __restrict__ out) {
  __shared__ __align__(16) float lds[BK * LDX * 2 + BK * 4];  // 17 KB union

  if (blockIdx.x >= NBLK_REC) {
    // ===================== GEMM role (R5 verbatim) =====================
    float* Xs = lds;                  // [kk][row], row-padded
    float* Ws = lds + BK * LDX;       // [kk][col]
    float* Wgs = lds + 2 * BK * LDX;  // [kk][gate]

    const int tid = threadIdx.x;
    const int gblk = blockIdx.x - NBLK_REC;
    const int tx = tid & 15, ty = tid >> 4;        // 16x16 thread grid
    const int r_st = tid >> 1, kh = (tid & 1) * 8; // X staging role
    const int wk = tid >> 4, wn = (tid & 15) * 8;  // W staging role
    const int r2 = tid >> 1, gp = (tid & 1) * 2;   // gate compute role

    const size_t rowbase = (size_t)gblk * 128;

    float acc[8][8] = {};
    float ga = 0.f, gb = 0.f;

    for (int kc = 0; kc < 256; kc += BK) {
      const float4 xa = *(const float4*)&X[(rowbase + r_st) * 256 + kc + kh];
      const float4 xb = *(const float4*)&X[(rowbase + r_st) * 256 + kc + kh + 4];
      const float4 wa = *(const float4*)&W1[(size_t)(kc + wk) * 128 + wn];
      const float4 wb = *(const float4*)&W1[(size_t)(kc + wk) * 128 + wn + 4];
      float wgv = 0.f;
      if (tid < 64) {
        const int kk = tid >> 2, g = tid & 3;
        const float* w = (g == 0) ? Wf : (g == 1) ? Wi : (g == 2) ? Wg : Wo;
        wgv = w[kc + kk];
      }
      __syncthreads();
      Xs[(kh + 0) * LDX + r_st] = xa.x;
      Xs[(kh + 1) * LDX + r_st] = xa.y;
      Xs[(kh + 2) * LDX + r_st] = xa.z;
      Xs[(kh + 3) * LDX + r_st] = xa.w;
      Xs[(kh + 4) * LDX + r_st] = xb.x;
      Xs[(kh + 5) * LDX + r_st] = xb.y;
      Xs[(kh + 6) * LDX + r_st] = xb.z;
      Xs[(kh + 7) * LDX + r_st] = xb.w;
      *(float4*)&Ws[wk * LDX + wn] = wa;
      *(float4*)&Ws[wk * LDX + wn + 4] = wb;
      if (tid < 64) Wgs[tid] = wgv;
      __syncthreads();

#pragma unroll
      for (int kk = 0; kk < BK; ++kk) {
        const float4 a0 = *(const float4*)&Xs[kk * LDX + ty * 8];
        const float4 a1 = *(const float4*)&Xs[kk * LDX + ty * 8 + 4];
        const float4 c0 = *(const float4*)&Ws[kk * LDX + tx * 8];
        const float4 c1 = *(const float4*)&Ws[kk * LDX + tx * 8 + 4];
        const float av[8] = {a0.x, a0.y, a0.z, a0.w, a1.x, a1.y, a1.z, a1.w};
        const float bv[8] = {c0.x, c0.y, c0.z, c0.w, c1.x, c1.y, c1.z, c1.w};
#pragma unroll
        for (int i = 0; i < 8; ++i)
#pragma unroll
          for (int j = 0; j < 8; ++j)
            acc[i][j] = fmaf(av[i], bv[j], acc[i][j]);
        const float xv = Xs[kk * LDX + r2];
        ga = fmaf(xv, Wgs[kk * 4 + gp], ga);
        gb = fmaf(xv, Wgs[kk * 4 + gp + 1], gb);
      }
    }

    float bias[8];
    {
      const float4 u0 = *(const float4*)&b1p[tx * 8];
      const float4 u1 = *(const float4*)&b1p[tx * 8 + 4];
      bias[0] = u0.x; bias[1] = u0.y; bias[2] = u0.z; bias[3] = u0.w;
      bias[4] = u1.x; bias[5] = u1.y; bias[6] = u1.z; bias[7] = u1.w;
    }
#pragma unroll
    for (int i = 0; i < 8; ++i) {
      const size_t row = rowbase + ty * 8 + i;
      float4 o0, o1;
      o0.x = acc[i][0] + bias[0]; o0.y = acc[i][1] + bias[1];
      o0.z = acc[i][2] + bias[2]; o0.w = acc[i][3] + bias[3];
      o1.x = acc[i][4] + bias[4]; o1.y = acc[i][5] + bias[5];
      o1.z = acc[i][6] + bias[6]; o1.w = acc[i][7] + bias[7];
      *(float4*)&PRE[row * PRE_STRIDE + tx * 8] = o0;
      *(float4*)&PRE[row * PRE_STRIDE + tx * 8 + 4] = o1;
    }
    {
      const float ab = (gp == 0) ? bfp[0] : bgp[0];
      const float bb2 = (gp == 0) ? bip[0] : bop[0];
      float2 og;
      og.x = ga + ab; og.y = gb + bb2;
      *(float2*)&PRE[(rowbase + r2) * PRE_STRIDE + 128 + gp] = og;
    }

    // -------- publish: all stores drained (barrier implies vmcnt(0)),
    // L2 written back to L3, then release-increment this block's flag. ----
    __syncthreads();
    if (tid == 0) {
      __threadfence();
      __hip_atomic_fetch_add(&g_flags[gblk], 1u, __ATOMIC_RELEASE,
                             __HIP_MEMORY_SCOPE_AGENT);
    }
    return;
  }

  // ======================= REC role (R5 verbatim + waits) ==================
  const int l = threadIdx.x;
  if (l >= 64) return;  // 1 wave per chain
  float* h1s = lds;     // 128 floats of the union

  const int b = blockIdx.x;
  const int m = l & 31, half = l >> 5;
  const int g = m >> 3;             // my gate group: 0=f 1=i 2=g 3=o
  const int g8 = g * 8;             // first column of my group

  // W2 fragment in registers: lane (m,half) holds W2[half*64+u][m]
  float w2r[64];
#pragma unroll
  for (int u = 0; u < 64; ++u) w2r[u] = W2[(size_t)(half * 64 + u) * 32 + m];
  const float4 b2a = *(const float4*)&b2[g8];
  const float4 b2b = *(const float4*)&b2[g8 + 4];
  const float2 s1 = *(const float2*)&aux[2 * l];
  const float4 sg = *(const float4*)&aux[128];  // sf, si, sg, so

  const unsigned target =
      __hip_atomic_load(&g_epoch, __ATOMIC_RELAXED, __HIP_MEMORY_SCOPE_AGENT);
  const int hb = (b >= 128) ? 1 : 0;  // my half-row producer parity

  // wait for rows 0 and 1 (producers 2*0+hb, 2*1+hb)
  spin_flag(&g_flags[0 + hb], target);
  spin_flag(&g_flags[2 + hb], target);

  float h = 0.f, c = 0.f;

  const float* pr0 = PRE + (size_t)b * PRE_STRIDE;
  const size_t ts = (size_t)BATCH * PRE_STRIDE;

  // depth-2 rotating prefetch
  float2 p0 = *(const float2*)(pr0 + 0 * ts + 2 * l);
  float4 g0 = *(const float4*)(pr0 + 0 * ts + 128);
  float2 p1 = *(const float2*)(pr0 + 1 * ts + 2 * l);
  float4 g1 = *(const float4*)(pr0 + 1 * ts + 128);

  const float4* h1p = (const float4*)&h1s[half * 64];

  for (int t = 0; t < SEQ; ++t) {
    const int tn = (t + 2 < SEQ) ? (t + 2) : (SEQ - 1);
    // early flag probe for row tn — acquire; latency hides under the dot
    const unsigned fv = __hip_atomic_load(
        &g_flags[2 * tn + hb], __ATOMIC_ACQUIRE, __HIP_MEMORY_SCOPE_AGENT);

    // h1 = relu(pre + h*s1)
    const float h10 = fmaxf(fmaf(h, s1.x, p0.x), 0.f);
    const float h11 = fmaxf(fmaf(h, s1.y, p0.y), 0.f);

    // publish h1 (the step's only LDS write); DS pipe is in-order per wave.
    ((float2*)h1s)[l] = make_float2(h10, h11);
    asm volatile("" ::: "memory");  // compiler barrier only — no s_waitcnt

    // classical gates — independent VALU work overlapping LDS latency
    const float zf = fmaf(h, sg.x, g0.x);
    const float zi = fmaf(h, sg.y, g0.y);
    const float zg = fmaf(h, sg.z, g0.z);
    const float zo = fmaf(h, sg.w, g0.w);
    const float cf = sigmoid_f(zf);
    const float ci = sigmoid_f(zi);
    const float cg = tanh_f(zg);
    const float co = sigmoid_f(zo);

    // row tn must be published before its prefetch issues (slow path rare)
    if (fv < target) spin_flag(&g_flags[2 * tn + hb], target);

    // rotate prefetch (depth 2)
    p0 = p1; g0 = g1;
    p1 = *(const float2*)(pr0 + (size_t)tn * ts + 2 * l);
    g1 = *(const float4*)(pr0 + (size_t)tn * ts + 128);

    // partial[m,half] = sum over my K-half of h1[j]*W2[j][m]
    float q0 = 0.f, q1 = 0.f, q2 = 0.f, q3 = 0.f;
#pragma unroll
    for (int jj = 0; jj < 16; ++jj) {
      const float4 hv = h1p[jj];
      q0 = fmaf(hv.x, w2r[4 * jj + 0], q0);
      q1 = fmaf(hv.y, w2r[4 * jj + 1], q1);
      q2 = fmaf(hv.z, w2r[4 * jj + 2], q2);
      q3 = fmaf(hv.w, w2r[4 * jj + 3], q3);
    }
    const float part = (q0 + q1) + (q2 + q3);

    // ONE pipelined 16-shfl burst: both halves' partials for my group's 8 m's
    const float a0 = __shfl(part, g8 + 0, 64), b0 = __shfl(part, 32 + g8 + 0, 64);
    const float a1 = __shfl(part, g8 + 1, 64), b1 = __shfl(part, 32 + g8 + 1, 64);
    const float a2 = __shfl(part, g8 + 2, 64), b2s = __shfl(part, 32 + g8 + 2, 64);
    const float a3 = __shfl(part, g8 + 3, 64), b3 = __shfl(part, 32 + g8 + 3, 64);
    const float a4 = __shfl(part, g8 + 4, 64), b4 = __shfl(part, 32 + g8 + 4, 64);
    const float a5 = __shfl(part, g8 + 5, 64), b5 = __shfl(part, 32 + g8 + 5, 64);
    const float a6 = __shfl(part, g8 + 6, 64), b6 = __shfl(part, 32 + g8 + 6, 64);
    const float a7 = __shfl(part, g8 + 7, 64), b7 = __shfl(part, 32 + g8 + 7, 64);

    // theta + cos, per-lane redundant (every lane evaluates ITS group)
    const float e0 = __cosf(a0 + b0 + b2a.x);
    const float e1 = __cosf(a1 + b1 + b2a.y);
    const float e2 = __cosf(a2 + b2s + b2a.z);
    const float e3 = __cosf(a3 + b3 + b2a.w);
    const float e4 = __cosf(a4 + b4 + b2b.x);
    const float e5 = __cosf(a5 + b5 + b2b.y);
    const float e6 = __cosf(a6 + b6 + b2b.z);
    const float e7 = __cosf(a7 + b7 + b2b.w);
    float p = e0, s = e0;
    p *= e1; s += p;
    p *= e2; s += p;
    p *= e3; s += p;
    p *= e4; s += p;
    p *= e5; s += p;
    p *= e6; s += p;
    p *= e7; s += p;
    const float qv = s * 0.125f;

    // one quantum activation per lane (group 2: tanh = 2*sigmoid(2x)-1)
    const float qarg = (g == 2) ? (2.0f * qv) : qv;
    const float qs = sigmoid_f(qarg);
    const float av = (g == 2) ? (2.0f * qs - 1.0f) : qs;

    // collect the 4 gate scalars via v_readlane (VALU, uniform lane indices)
    const float aF = readlane_f(av, 0);
    const float aI = readlane_f(av, 8);
    const float aG = readlane_f(av, 16);
    const float aO = readlane_f(av, 24);

    const float f  = 0.5f * (cf + aF);
    const float ii = 0.5f * (ci + aI);
    const float gg = 0.5f * (cg + aG);
    const float oo = 0.5f * (co + aO);

    c = fmaf(f, c, ii * gg);
    h = oo * tanh_f(c);

    float4 hv4o; hv4o.x = h; hv4o.y = h; hv4o.z = h; hv4o.w = h;
    *(float4*)(out + ((size_t)t * BATCH + b) * 256 + 4 * l) = hv4o;
  }

  // final (hx, cx)
  float4 hq; hq.x = h; hq.y = h; hq.z = h; hq.w = h;
  float4 cq; cq.x = c; cq.y = c; cq.z = c; cq.w = c;
  *(float4*)(out + (size_t)SEQ * BATCH * 256 + (size_t)b * 256 + 4 * l) = hq;
  *(float4*)(out + (size_t)SEQ * BATCH * 256 + (size_t)BATCH * 256 +
             (size_t)b * 256 + 4 * l) = cq;
}

// ---------------------------------------------------------------------------
extern "C" void kernel_launch(void* const* d_in, const int* in_sizes, int n_in,
                              void* d_out, int out_size, void* d_ws,
                              size_t ws_size, hipStream_t stream) {
  const float* X  = (const float*)d_in[0];
  const float* W1 = (const float*)d_in[1];
  const float* b1 = (const float*)d_in[2];
  const float* W2 = (const float*)d_in[3];
  const float* b2 = (const float*)d_in[4];
  const float* Wf = (const float*)d_in[5];
  const float* bf = (const float*)d_in[6];
  const float* Wi = (const float*)d_in[7];
  const float* bi = (const float*)d_in[8];
  const float* Wg = (const float*)d_in[9];
  const float* bg = (const float*)d_in[10];
  const float* Wo = (const float*)d_in[11];
  const float* bo = (const float*)d_in[12];

  float* ws  = (float*)d_ws;
  float* PRE = ws;
  float* aux = ws + AUX_OFF;
  float* out = (float*)d_out;

  prep_kernel<<<1, 256, 0, stream>>>(W1, Wf, Wi, Wg, Wo, bf, bi, bg, bo, aux);
  fused_kernel<<<NBLK_REC + NBLK_GEMM, 256, 0, stream>>>(
      X, W1, b1, Wf, Wi, Wg, Wo, bf, bi, bg, bo, W2, b2, aux, PRE, out);
}

// Round 7
// 767.057 us; speedup vs baseline: 1.8502x; 1.8447x over previous
//
#include <hip/hip_runtime.h>

#define SEQ 512
#define BATCH 256
#define INDIM 256
#define MLP 128
#define M_ROWS (SEQ * BATCH)        // 131072
#define PRE_STRIDE 136              // 128 mlp-pre + 4 gate-pre + 4 pad
#define AUX_OFF ((size_t)M_ROWS * PRE_STRIDE)  // in floats

// ---------------------------------------------------------------------------
// R13: fusion abandoned (R10/R11/R12 post-mortems: one regalloc for two roles
// + spin-guard silent-corruption under contention). Back to the proven
// 3-kernel structure; two independent, separately-attributable improvements:
//   gemm: R5 + register prefetch of chunk k+1 after chunk k's write-barrier
//         (R9's idea WITHOUT the av[gr] scratch bomb) + waves_per_eu(1,3)
//         so the prefetch regs don't trigger allocator spill (R12 proved
//         this attribute is the effective knob, launch_bounds' 2nd arg is not).
//   rec:  R5 + the R8-validated cross-lane tail (shfl_xor fold -> ONE cos
//         per lane -> 8-shfl gather). Bitwise-identical float sequence.
// ---------------------------------------------------------------------------

// ---------------------------------------------------------------------------
// Kernel 1: prep — column sums of the recurrent halves of W1 and gate weights.
// ---------------------------------------------------------------------------
__global__ __launch_bounds__(256) void prep_kernel(
    const float* __restrict__ W1,
    const float* __restrict__ Wf, const float* __restrict__ Wi,
    const float* __restrict__ Wg, const float* __restrict__ Wo,
    const float* __restrict__ bf, const float* __restrict__ bi,
    const float* __restrict__ bg, const float* __restrict__ bo,
    float* __restrict__ aux) {
  const int tid = threadIdx.x;
  if (tid < 128) {
    float s = 0.f;
    for (int k = 0; k < 256; ++k) s += W1[(size_t)(256 + k) * 128 + tid];
    aux[tid] = s;
  } else if (tid < 132) {
    const int g = tid - 128;
    const float* w = (g == 0) ? Wf : (g == 1) ? Wi : (g == 2) ? Wg : Wo;
    float s = 0.f;
    for (int k = 0; k < 256; ++k) s += w[256 + k];
    aux[128 + g] = s;
  } else if (tid < 136) {
    const int g = tid - 132;
    const float* bp = (g == 0) ? bf : (g == 1) ? bi : (g == 2) ? bg : bo;
    aux[132 + g] = bp[0];
  }
}

// ---------------------------------------------------------------------------
// Kernel 2: big fp32 GEMM — R5 structure + software-pipelined staging.
// R9 post-mortem: the ONLY poison there was av[gr] (runtime-indexed local
// array -> scratch, rule #20). The pipeline itself was never tested clean.
// Here: gate dot keeps R5's ds_read (xv = Xs[kk][r2]); staging loads for
// chunk kc+BK issue AFTER chunk kc's write-barrier, consumed at the next
// iteration's top -> ~600-900 cy VMEM latency hides under ~2000 cy compute.
// waves_per_eu(1,3): VGPR budget 512/3 = 170 >= acc(64)+prefetch(17)+working,
// prevents the allocator's default occupancy squeeze from spilling acc.
// ---------------------------------------------------------------------------
#define BK 16
#define LDX 132  // padded LDS row stride (words)

__global__ __attribute__((amdgpu_waves_per_eu(1, 3))) __launch_bounds__(256)
void gemm_kernel(
    const float* __restrict__ X,    // [M_ROWS][256]
    const float* __restrict__ W1,   // [512][128] (only rows 0..255 used here)
    const float* __restrict__ b1p,  // [128]
    const float* __restrict__ Wf, const float* __restrict__ Wi,
    const float* __restrict__ Wg, const float* __restrict__ Wo,
    const float* __restrict__ bfp, const float* __restrict__ bip,
    const float* __restrict__ bgp, const float* __restrict__ bop,
    float* __restrict__ PRE) {
  __shared__ __align__(16) float Xs[BK * LDX];   // [kk][row], row-padded
  __shared__ __align__(16) float Ws[BK * LDX];   // [kk][col]
  __shared__ float Wgs[BK * 4];                  // [kk][gate]

  const int tid = threadIdx.x;
  const int blk = blockIdx.x;
  const int tx = tid & 15, ty = tid >> 4;        // 16x16 thread grid
  const int r_st = tid >> 1, kh = (tid & 1) * 8; // X staging role
  const int wk = tid >> 4, wn = (tid & 15) * 8;  // W staging role
  const int r2 = tid >> 1, gp = (tid & 1) * 2;   // gate compute role (R5)

  const size_t rowbase = (size_t)blk * 128;

  float acc[8][8] = {};
  float ga = 0.f, gb = 0.f;

  // -------- prologue: prefetch chunk 0 into registers --------
  float4 xa = *(const float4*)&X[(rowbase + r_st) * 256 + 0 + kh];
  float4 xb = *(const float4*)&X[(rowbase + r_st) * 256 + 0 + kh + 4];
  float4 wa = *(const float4*)&W1[(size_t)(0 + wk) * 128 + wn];
  float4 wb = *(const float4*)&W1[(size_t)(0 + wk) * 128 + wn + 4];
  float wgv = 0.f;
  if (tid < 64) {
    const int kk = tid >> 2, g = tid & 3;
    const float* w = (g == 0) ? Wf : (g == 1) ? Wi : (g == 2) ? Wg : Wo;
    wgv = w[0 + kk];
  }

  for (int kc = 0; kc < 256; kc += BK) {
    __syncthreads();  // previous chunk's LDS reads retired before overwrite
    Xs[(kh + 0) * LDX + r_st] = xa.x;
    Xs[(kh + 1) * LDX + r_st] = xa.y;
    Xs[(kh + 2) * LDX + r_st] = xa.z;
    Xs[(kh + 3) * LDX + r_st] = xa.w;
    Xs[(kh + 4) * LDX + r_st] = xb.x;
    Xs[(kh + 5) * LDX + r_st] = xb.y;
    Xs[(kh + 6) * LDX + r_st] = xb.z;
    Xs[(kh + 7) * LDX + r_st] = xb.w;
    *(float4*)&Ws[wk * LDX + wn] = wa;
    *(float4*)&Ws[wk * LDX + wn + 4] = wb;
    if (tid < 64) Wgs[tid] = wgv;
    __syncthreads();

    // -------- prefetch chunk kc+BK (latency hides under compute below) ----
    if (kc + BK < 256) {
      const int kn = kc + BK;
      xa = *(const float4*)&X[(rowbase + r_st) * 256 + kn + kh];
      xb = *(const float4*)&X[(rowbase + r_st) * 256 + kn + kh + 4];
      wa = *(const float4*)&W1[(size_t)(kn + wk) * 128 + wn];
      wb = *(const float4*)&W1[(size_t)(kn + wk) * 128 + wn + 4];
      if (tid < 64) {
        const int kk = tid >> 2, g = tid & 3;
        const float* w = (g == 0) ? Wf : (g == 1) ? Wi : (g == 2) ? Wg : Wo;
        wgv = w[kn + kk];
      }
    }

#pragma unroll
    for (int kk = 0; kk < BK; ++kk) {
      const float4 a0 = *(const float4*)&Xs[kk * LDX + ty * 8];
      const float4 a1 = *(const float4*)&Xs[kk * LDX + ty * 8 + 4];
      const float4 c0 = *(const float4*)&Ws[kk * LDX + tx * 8];
      const float4 c1 = *(const float4*)&Ws[kk * LDX + tx * 8 + 4];
      const float av[8] = {a0.x, a0.y, a0.z, a0.w, a1.x, a1.y, a1.z, a1.w};
      const float bv[8] = {c0.x, c0.y, c0.z, c0.w, c1.x, c1.y, c1.z, c1.w};
#pragma unroll
      for (int i = 0; i < 8; ++i)
#pragma unroll
        for (int j = 0; j < 8; ++j)
          acc[i][j] = fmaf(av[i], bv[j], acc[i][j]);
      const float xv = Xs[kk * LDX + r2];   // R5 verbatim — compile-time-safe
      ga = fmaf(xv, Wgs[kk * 4 + gp], ga);
      gb = fmaf(xv, Wgs[kk * 4 + gp + 1], gb);
    }
  }

  float bias[8];
  {
    const float4 u0 = *(const float4*)&b1p[tx * 8];
    const float4 u1 = *(const float4*)&b1p[tx * 8 + 4];
    bias[0] = u0.x; bias[1] = u0.y; bias[2] = u0.z; bias[3] = u0.w;
    bias[4] = u1.x; bias[5] = u1.y; bias[6] = u1.z; bias[7] = u1.w;
  }
#pragma unroll
  for (int i = 0; i < 8; ++i) {
    const size_t row = rowbase + ty * 8 + i;
    float4 o0, o1;
    o0.x = acc[i][0] + bias[0]; o0.y = acc[i][1] + bias[1];
    o0.z = acc[i][2] + bias[2]; o0.w = acc[i][3] + bias[3];
    o1.x = acc[i][4] + bias[4]; o1.y = acc[i][5] + bias[5];
    o1.z = acc[i][6] + bias[6]; o1.w = acc[i][7] + bias[7];
    *(float4*)&PRE[row * PRE_STRIDE + tx * 8] = o0;
    *(float4*)&PRE[row * PRE_STRIDE + tx * 8 + 4] = o1;
  }
  {
    const float ab = (gp == 0) ? bfp[0] : bgp[0];
    const float bb2 = (gp == 0) ? bip[0] : bop[0];
    float2 og;
    og.x = ga + ab; og.y = gb + bb2;
    *(float2*)&PRE[(rowbase + r2) * PRE_STRIDE + 128 + gp] = og;
  }
}

// ---------------------------------------------------------------------------
// Kernel 3: serial recurrence — R5 body + R8-validated cross-lane tail.
// Tail: part + shfl_xor(32) gives every lane the FULL column sum (commutative
// add -> bitwise-identical on both halves); ONE __cosf per lane (its own
// column m); 8-shfl gather of the group's cos values; product chain in the
// exact R5 order. Replaces 16 shfl + 8 cos with 9 shfl + 1 cos per step.
// R8 passed with exactly this tail (absmax 0.001953125).
// R8 post-mortem stands: NO global_load_lds staging here (compiler-forced
// vmcnt(0) drain per step). Depth-2 register prefetch retained.
// ---------------------------------------------------------------------------
__device__ __forceinline__ float sigmoid_f(float x) {
  return __fdividef(1.0f, 1.0f + __expf(-x));
}
__device__ __forceinline__ float tanh_f(float x) {
  const float e = __expf(-2.0f * x);
  return __fdividef(1.0f - e, 1.0f + e);
}
__device__ __forceinline__ float readlane_f(float v, int lane) {
  return __int_as_float(__builtin_amdgcn_readlane(__float_as_int(v), lane));
}

__global__ __attribute__((amdgpu_waves_per_eu(1, 1))) __launch_bounds__(64)
void rec_kernel(
    const float* __restrict__ PRE, const float* __restrict__ W2,
    const float* __restrict__ b2, const float* __restrict__ aux,
    float* __restrict__ out) {
  __shared__ __align__(16) float h1s[128];

  const int l = threadIdx.x;
  const int b = blockIdx.x;
  const int m = l & 31, half = l >> 5;
  const int g = m >> 3;             // my gate group: 0=f 1=i 2=g 3=o
  const int g8 = g * 8;             // first column of my group

  // W2 fragment in registers: lane (m,half) holds W2[half*64+u][m]
  float w2r[64];
#pragma unroll
  for (int u = 0; u < 64; ++u) w2r[u] = W2[(size_t)(half * 64 + u) * 32 + m];
  const float b2m = b2[m];          // my own column's bias (R8 tail)
  const float2 s1 = *(const float2*)&aux[2 * l];
  const float4 sg = *(const float4*)&aux[128];  // sf, si, sg, so

  float h = 0.f, c = 0.f;

  const float* pr0 = PRE + (size_t)b * PRE_STRIDE;
  const size_t ts = (size_t)BATCH * PRE_STRIDE;

  // depth-2 rotating prefetch
  float2 p0 = *(const float2*)(pr0 + 0 * ts + 2 * l);
  float4 g0 = *(const float4*)(pr0 + 0 * ts + 128);
  float2 p1 = *(const float2*)(pr0 + 1 * ts + 2 * l);
  float4 g1 = *(const float4*)(pr0 + 1 * ts + 128);

  const float4* h1p = (const float4*)&h1s[half * 64];

  for (int t = 0; t < SEQ; ++t) {
    // h1 = relu(pre + h*s1)
    const float h10 = fmaxf(fmaf(h, s1.x, p0.x), 0.f);
    const float h11 = fmaxf(fmaf(h, s1.y, p0.y), 0.f);

    // publish h1 (the step's only LDS write); DS pipe is in-order per wave,
    // so the later ds_reads observe it without an explicit waitcnt.
    ((float2*)h1s)[l] = make_float2(h10, h11);
    asm volatile("" ::: "memory");  // compiler barrier only — no s_waitcnt

    // classical gates — independent VALU work placed to overlap LDS latency
    const float zf = fmaf(h, sg.x, g0.x);
    const float zi = fmaf(h, sg.y, g0.y);
    const float zg = fmaf(h, sg.z, g0.z);
    const float zo = fmaf(h, sg.w, g0.w);
    const float cf = sigmoid_f(zf);
    const float ci = sigmoid_f(zi);
    const float cg = tanh_f(zg);
    const float co = sigmoid_f(zo);
    // rotate prefetch (depth 2)
    p0 = p1; g0 = g1;
    const int tn = (t + 2 < SEQ) ? (t + 2) : (SEQ - 1);
    p1 = *(const float2*)(pr0 + (size_t)tn * ts + 2 * l);
    g1 = *(const float4*)(pr0 + (size_t)tn * ts + 128);

    // partial[m,half] = sum over my K-half of h1[j]*W2[j][m]
    float q0 = 0.f, q1 = 0.f, q2 = 0.f, q3 = 0.f;
#pragma unroll
    for (int jj = 0; jj < 16; ++jj) {
      const float4 hv = h1p[jj];
      q0 = fmaf(hv.x, w2r[4 * jj + 0], q0);
      q1 = fmaf(hv.y, w2r[4 * jj + 1], q1);
      q2 = fmaf(hv.z, w2r[4 * jj + 2], q2);
      q3 = fmaf(hv.w, w2r[4 * jj + 3], q3);
    }
    const float part = (q0 + q1) + (q2 + q3);

    // ---- R8-validated tail: fold halves, one cos per lane, 8-shfl gather --
    const float full = part + __shfl_xor(part, 32, 64);  // both halves: a+b
    const float cm = __cosf(full + b2m);                 // my column's cos
    const int sb = (l & 32) + g8;                        // gather in my half
    const float e0 = __shfl(cm, sb + 0, 64);
    const float e1 = __shfl(cm, sb + 1, 64);
    const float e2 = __shfl(cm, sb + 2, 64);
    const float e3 = __shfl(cm, sb + 3, 64);
    const float e4 = __shfl(cm, sb + 4, 64);
    const float e5 = __shfl(cm, sb + 5, 64);
    const float e6 = __shfl(cm, sb + 6, 64);
    const float e7 = __shfl(cm, sb + 7, 64);
    float p = e0, s = e0;                                // exact R5 order
    p *= e1; s += p;
    p *= e2; s += p;
    p *= e3; s += p;
    p *= e4; s += p;
    p *= e5; s += p;
    p *= e6; s += p;
    p *= e7; s += p;
    const float qv = s * 0.125f;

    // one quantum activation per lane (group 2: tanh = 2*sigmoid(2x)-1)
    const float qarg = (g == 2) ? (2.0f * qv) : qv;
    const float qs = sigmoid_f(qarg);
    const float av = (g == 2) ? (2.0f * qs - 1.0f) : qs;

    // collect the 4 gate scalars via v_readlane (VALU, uniform lane indices)
    const float aF = readlane_f(av, 0);
    const float aI = readlane_f(av, 8);
    const float aG = readlane_f(av, 16);
    const float aO = readlane_f(av, 24);

    const float f  = 0.5f * (cf + aF);
    const float ii = 0.5f * (ci + aI);
    const float gg = 0.5f * (cg + aG);
    const float oo = 0.5f * (co + aO);

    c = fmaf(f, c, ii * gg);
    h = oo * tanh_f(c);

    float4 hv4o; hv4o.x = h; hv4o.y = h; hv4o.z = h; hv4o.w = h;
    *(float4*)(out + ((size_t)t * BATCH + b) * 256 + 4 * l) = hv4o;
  }

  // final (hx, cx)
  float4 hq; hq.x = h; hq.y = h; hq.z = h; hq.w = h;
  float4 cq; cq.x = c; cq.y = c; cq.z = c; cq.w = c;
  *(float4*)(out + (size_t)SEQ * BATCH * 256 + (size_t)b * 256 + 4 * l) = hq;
  *(float4*)(out + (size_t)SEQ * BATCH * 256 + (size_t)BATCH * 256 +
             (size_t)b * 256 + 4 * l) = cq;
}

// ---------------------------------------------------------------------------
extern "C" void kernel_launch(void* const* d_in, const int* in_sizes, int n_in,
                              void* d_out, int out_size, void* d_ws,
                              size_t ws_size, hipStream_t stream) {
  const float* X  = (const float*)d_in[0];
  const float* W1 = (const float*)d_in[1];
  const float* b1 = (const float*)d_in[2];
  const float* W2 = (const float*)d_in[3];
  const float* b2 = (const float*)d_in[4];
  const float* Wf = (const float*)d_in[5];
  const float* bf = (const float*)d_in[6];
  const float* Wi = (const float*)d_in[7];
  const float* bi = (const float*)d_in[8];
  const float* Wg = (const float*)d_in[9];
  const float* bg = (const float*)d_in[10];
  const float* Wo = (const float*)d_in[11];
  const float* bo = (const float*)d_in[12];

  float* ws  = (float*)d_ws;
  float* PRE = ws;
  float* aux = ws + AUX_OFF;
  float* out = (float*)d_out;

  prep_kernel<<<1, 256, 0, stream>>>(W1, Wf, Wi, Wg, Wo, bf, bi, bg, bo, aux);
  gemm_kernel<<<M_ROWS / 128, 256, 0, stream>>>(X, W1, b1, Wf, Wi, Wg, Wo,
                                                bf, bi, bg, bo, PRE);
  rec_kernel<<<BATCH, 64, 0, stream>>>(PRE, W2, b2, aux, out);
}